// Round 1
// 150.144 us; speedup vs baseline: 1.0891x; 1.0891x over previous
//
#include <hip/hip_runtime.h>

// Problem constants (fixed by reference).
#define TT   512
#define BB   2048
#define NTAG 16
#define CH   8              // timesteps staged per chunk
#define NCH  (TT / CH)      // 64 chunks
#define BBN  (BB * NTAG)

typedef float v2f __attribute__((ext_vector_type(2)));

// ---------- DPP helpers ----------
#define DPP_XOR1  0xB1    // quad_perm [1,0,3,2] : lane ^ 1
#define DPP_XOR2  0x4E    // quad_perm [2,3,0,1] : lane ^ 2
#define DPP_XOR3  0x1B    // quad_perm [3,2,1,0] : lane ^ 3
#define DPP_ROR4  0x124   // src gate g+3 == g-1 (verified round 2)
#define DPP_ROR8  0x128   // src gate g+2
#define DPP_ROR12 0x12C   // src gate g+1

template<int CTRL>
__device__ __forceinline__ float dppf(float v) {
    int r = __builtin_amdgcn_update_dpp(0, __builtin_bit_cast(int, v),
                                        CTRL, 0xF, 0xF, true);
    return __builtin_bit_cast(float, r);
}

// Producer/consumer split:
//   waves 0,1 : recurrent scan (latency-bound serial chain), h -> LDS ring
//   waves 2,3 : tag projection + log_softmax + global store (throughput-bound)
// One block = 8 batch elems (4 per producer wave). 256 blocks = 1 block/CU.
// __launch_bounds__(256,1): we only ever want 1 block/CU -> give the
// register allocator the full budget so the unrolled chunk can rename freely.
__global__ __launch_bounds__(256, 1) void qlstm_fused(
    const float* __restrict__ x,        // (T,B,8)
    const float* __restrict__ w_gates,  // (4,4,12)
    const float* __restrict__ b_gates,  // (4,4)
    const float* __restrict__ rx_theta, // (4,4)
    const float* __restrict__ w_tag,    // (16,4)
    const float* __restrict__ b_tag,    // (16,)
    float* __restrict__ out)            // (T,B,16)
{
    __shared__ float4 lds4[2][2][CH][8];     // x staging  [prod-wave][buf][step][slot]
    __shared__ float  hbuf[2][2][CH][64];    // h ring     [prod-wave][buf][step][lane]

    const int tid = threadIdx.x;
    const int wv  = tid >> 6;          // 0..3
    const int l   = tid & 63;
    const int e   = l >> 4;
    const int g   = (l >> 2) & 3;
    const int k   = l & 3;

    const float IV  = 0.15915494309189535f;   // 1/(2pi): v_cos takes revolutions
    const float L2E = 1.44269504088896f;
    const float LN2 = 0.69314718056f;

    if (wv < 2) {
        // ============================ producer ============================
        const int b0 = blockIdx.x * 8 + wv * 4;

        const float* wrow = w_gates + (g * 4 + k) * 12;
        // packed x-weights (pairs match ds_read_b128 register adjacency)
        const v2f wp0 = { wrow[0] * IV, wrow[1] * IV };
        const v2f wp1 = { wrow[2] * IV, wrow[3] * IV };
        const v2f wp2 = { wrow[4] * IV, wrow[5] * IV };
        const v2f wp3 = { wrow[6] * IV, wrow[7] * IV };
        const float wh0 = wrow[8 + (k ^ 0)] * IV;
        const float wh1 = wrow[8 + (k ^ 1)] * IV;
        const float wh2 = wrow[8 + (k ^ 2)] * IV;
        const float wh3 = wrow[8 + (k ^ 3)] * IV;
        const v2f bp = { (b_gates[g * 4 + k] + rx_theta[g * 4 + k]) * IV, 0.0f };

        // Branchless gate activation: odd deg-7 poly act = bA + q*P(q^2), q in [-1,1].
        // g==2 -> tanh (refit, err<=2e-4); else sigmoid (Taylor, err~2e-5).
        const bool gt = (g == 2);
        const float bA = gt ? 0.0f : 0.5f;
        const float d0 = gt ? 0.999904f  : 0.25f;
        const float d1 = gt ? -0.331065f : -0.0208333333f;
        const float d2 = gt ? 0.120472f  : 0.00208333333f;
        const float d3 = gt ? -0.027717f : -2.10813e-4f;

        // tanh(c) deg-11 odd poly, |c| <= 2.0703 (bounded by construction).
        const float u0 = 0.999160f,  u1 = -0.325289f, u2 = 0.112257f;
        const float u3 = -0.028766f, u4 = 0.0043665f, u5 = -0.00028186f;

        const bool k0 = (k == 0), k1 = (k == 1), k3 = (k == 3);
        const bool g0 = (g == 0), g2 = (g == 2), glo = (g < 2);

        // x staging: lane covers step (l>>3) of each chunk, 16B slot (l&7).
        const float* xlane = x + (size_t)(l >> 3) * (BB * 8)
                               + (size_t)b0 * 8 + (l & 7) * 4;
        const size_t CHOFF = (size_t)CH * BB * 8;
        float4* ldsw = (float4*)&lds4[wv][0][0][0];

        // ---- prologue: chunk0 -> buf0, chunk1 -> regs ----
        float4 reg = *(const float4*)(xlane);
        ldsw[l] = reg;
        reg = *(const float4*)(xlane + CHOFF);

        float4 xcA = lds4[wv][0][0][2 * e];
        float4 xcB = lds4[wv][0][0][2 * e + 1];

        float h = 0.f, c = 0.f, h1 = 0.f, h2 = 0.f, h3 = 0.f;

        for (int cc = 0; cc < NCH; ++cc) {
            const int cur = cc & 1;
            ldsw[(cur ^ 1) * 64 + l] = reg;          // stage chunk cc+1
            const int cn = (cc + 2 < NCH) ? cc + 2 : NCH - 1;
            reg = *(const float4*)(xlane + (size_t)cn * CHOFF);  // issue chunk cc+2

            #pragma unroll
            for (int i = 0; i < CH; ++i) {
                // prefetch x for next step (off-chain)
                const int nb = (i == CH - 1) ? (cur ^ 1) : cur;
                const int ns = (i + 1) & (CH - 1);
                const float4 xnA = lds4[wv][nb][ns][2 * e];
                const float4 xnB = lds4[wv][nb][ns][2 * e + 1];

                // off-chain: x-dot via packed f32
                const v2f a01 = { xcA.x, xcA.y }, a23 = { xcA.z, xcA.w };
                const v2f a45 = { xcB.x, xcB.y }, a67 = { xcB.z, xcB.w };
                v2f acc = __builtin_elementwise_fma(a01, wp0, bp);
                acc = __builtin_elementwise_fma(a23, wp1, acc);
                acc = __builtin_elementwise_fma(a45, wp2, acc);
                acc = __builtin_elementwise_fma(a67, wp3, acc);
                const float accx = acc.x + acc.y;

                // on-chain: h-dot as sequential fma string
                float ang = fmaf(h,  wh0, accx);
                ang = fmaf(h1, wh1, ang);
                ang = fmaf(h2, wh2, ang);
                ang = fmaf(h3, wh3, ang);

                const float C = __builtin_amdgcn_cosf(ang);   // cos(2*pi*ang)
                // wire-product via 3 parallel DPPs:
                // k0: m1*(m2*m3), k1: C*m1, k2: C*(m2*m3), k3: (C*m1)*(m2*m3)
                const float m1 = dppf<DPP_XOR1>(C);
                const float m2 = dppf<DPP_XOR2>(C);
                const float m3 = dppf<DPP_XOR3>(C);
                const float Bp = m2 * m3;
                const float pp = C * m1;
                const float X  = k0 ? m1 : (k3 ? pp : C);
                const float Y  = k1 ? m1 : Bp;
                const float q  = X * Y;                       // q in [-1,1]

                // gate activation: odd deg-7 poly (valid on ALL lanes)
                const float y  = q * q;
                const float y2 = y * y;
                const float tA = fmaf(y, d1, d0);
                const float tB = fmaf(y, d3, d2);
                const float P  = fmaf(y2, tB, tA);
                const float act = fmaf(q, P, bA);

                // Role rotation: every lane uses (act, g+1, g+2, g+3) as (f,i,g~,o).
                // Only g==0 lanes produce the TRUE c/h; others carry bounded garbage.
                const float rA = dppf<DPP_ROR12>(act);  // gate g+1
                const float rB = dppf<DPP_ROR8>(act);   // gate g+2
                const float rC = dppf<DPP_ROR4>(act);   // gate g+3
                c = fmaf(act, c, rA * rB);

                // tanh(c) deg-11 odd poly (Estrin); h_raw = (o*c)*P(c^2)
                const float cy  = c * c;
                const float cy2 = cy * cy;
                const float t1  = fmaf(cy, u1, u0);
                const float t2  = fmaf(cy, u3, u2);
                const float t3  = fmaf(cy, u5, u4);
                const float t4  = fmaf(cy2, t3, t2);
                const float Pc  = fmaf(cy2, t4, t1);
                const float voc = rC * c;
                const float h_raw = Pc * voc;

                // hand off h to the consumer wave (true h lives on g==0 lanes;
                // consumer reads slots e*16+k only -> write is off-chain)
                hbuf[wv][cur][i][l] = h_raw;

                // redistribute TRUE h (lives on g==0 lanes) to all gate quads
                const float r4  = dppf<DPP_ROR4>(h_raw);   // from lane g-1
                const float r8  = dppf<DPP_ROR8>(h_raw);   // from lane g-2
                const float r12 = dppf<DPP_ROR12>(h_raw);  // from lane g-3
                h = glo ? (g0 ? h_raw : r4) : (g2 ? r8 : r12);

                // h gather within wire-quad (feeds next h-dot)
                h1 = dppf<DPP_XOR1>(h);
                h2 = dppf<DPP_XOR2>(h);
                h3 = dppf<DPP_XOR3>(h);

                xcA = xnA; xcB = xnB;
            }
            __syncthreads();    // publish chunk cc; consumer lags one chunk
        }
    } else {
        // ============================ consumer ============================
        const int pw = wv - 2;                  // which producer wave we serve
        const int b0 = blockIdx.x * 8 + pw * 4;
        const int tag = g * 4 + k;              // lane owns one output tag

        // tag weights pre-scaled by log2(e): softmax runs in base 2 throughout
        const float wt0 = w_tag[tag * 4 + (k ^ 0)] * L2E;
        const float wt1 = w_tag[tag * 4 + (k ^ 1)] * L2E;
        const float wt2 = w_tag[tag * 4 + (k ^ 2)] * L2E;
        const float wt3 = w_tag[tag * 4 + (k ^ 3)] * L2E;
        const float bt  = b_tag[tag] * L2E;

        float* outp = out + (size_t)b0 * NTAG + l;   // 64 lanes = 256B per t
        const int hsl = e * 16 + k;             // g==0 slot of our (e,k)

        for (int cc = 0; cc < NCH; ++cc) {
            __syncthreads();                    // wait for producer chunk cc
            const int cur = cc & 1;

            #pragma unroll
            for (int i = 0; i < CH; ++i) {
                // broadcast read (4 g-lanes share one address: conflict-free)
                const float hv = hbuf[pw][cur][i][hsl];
                const float h1 = dppf<DPP_XOR1>(hv);
                const float h2 = dppf<DPP_XOR2>(hv);
                const float h3 = dppf<DPP_XOR3>(hv);

                // fused projection + log_softmax, base-2
                const float lgq = fmaf(hv, wt0, fmaf(h1, wt1, fmaf(h2, wt2,
                                     fmaf(h3, wt3, bt))));    // log2-scaled logit
                const float ex = __builtin_amdgcn_exp2f(lgq);
                float s = ex + dppf<DPP_XOR1>(ex);
                s = s + dppf<DPP_XOR2>(s);
                s = s + dppf<DPP_ROR4>(s);
                s = s + dppf<DPP_ROR8>(s);
                const float l2s = __builtin_amdgcn_logf(s);   // log2(s)

                *outp = (lgq - l2s) * LN2;
                outp += BBN;
            }
        }
    }
}

extern "C" void kernel_launch(void* const* d_in, const int* in_sizes, int n_in,
                              void* d_out, int out_size, void* d_ws, size_t ws_size,
                              hipStream_t stream) {
    const float* x        = (const float*)d_in[0];
    const float* w_gates  = (const float*)d_in[1];
    const float* b_gates  = (const float*)d_in[2];
    const float* rx_theta = (const float*)d_in[3];
    const float* w_tag    = (const float*)d_in[4];
    const float* b_tag    = (const float*)d_in[5];
    float* out = (float*)d_out;

    qlstm_fused<<<BB / 8, 256, 0, stream>>>(x, w_gates, b_gates, rx_theta,
                                            w_tag, b_tag, out);
}